// Round 2
// baseline (352.951 us; speedup 1.0000x reference)
//
#include <hip/hip_runtime.h>
#include <hip/hip_bf16.h>
#include <stdint.h>

#define Tdim 4096
#define Ndim 4096
#define Kdim 4096
#define K2   4160   // 4096 + 32 (low-rank concat) + 32 (zero pad to multiple of 64)
#define NSPLIT 16   // K-splits for the low-rank partial GEMM
#define NT   130    // K2 / 32 K-steps for the main GEMM

using f32x4  = __attribute__((ext_vector_type(4))) float;
using bf16x8 = __attribute__((ext_vector_type(8))) short;

// round-to-nearest-even f32 -> bf16 bits
__device__ inline ushort f2bf(float f) {
  union { float f; unsigned u; } v; v.f = f;
  unsigned lsb = (v.u >> 16) & 1u;
  v.u += 0x7fffu + lsb;
  return (ushort)(v.u >> 16);
}

__device__ inline unsigned pack2(float a, float b) {
  return (unsigned)f2bf(a) | ((unsigned)f2bf(b) << 16);
}

__device__ inline float qd(float v, float s) {   // quantize-dequantize
  return fminf(fmaxf(rintf(v / s), -8.f), 7.f) * s;
}

__device__ inline void async16(const void* g, void* l) {
  __builtin_amdgcn_global_load_lds(
      (const __attribute__((address_space(1))) unsigned int*)g,
      (__attribute__((address_space(3))) unsigned int*)l, 16, 0, 0);
}

// ---------------- K0: pdT[n][k] = bf16(pd[k][n])  (32 x 4096) ---------------
__global__ __launch_bounds__(256) void prep_pdT_kernel(
    const float* __restrict__ pd, ushort* __restrict__ pdT) {
  const int idx = blockIdx.x * 256 + threadIdx.x;   // 32*4096 threads
  const int n = idx >> 12;
  const int k = idx & 4095;
  pdT[(size_t)n * Kdim + k] = f2bf(pd[(size_t)k * 32 + n]);
}

// ========== K1: fused activation quant-dequant + low-rank partial GEMM ======
// grid (32 token-tiles, 16 k-splits); block covers 128 tokens x 256 k.
// Writes A[token][0..4095] (bf16 qdq values) and partials[split][T][32].
__global__ __launch_bounds__(256) void prep_a_kernel(
    const float* __restrict__ x, const float* __restrict__ smooth,
    const ushort* __restrict__ pdT, ushort* __restrict__ A,
    float* __restrict__ partials) {
  __shared__ __attribute__((aligned(16))) ushort sXS[128 * 136];  // xs (bf16) for MFMA
  __shared__ __attribute__((aligned(16))) ushort sQ[128 * 136];   // qdq(xs) for A
  const int tid  = threadIdx.x;
  const int lane = tid & 63;
  const int wave = tid >> 6;
  const int fr  = lane & 15;
  const int fkq = lane >> 4;
  const int fk  = fkq * 8;
  const int tok0 = blockIdx.x * 128;
  const int kc0  = blockIdx.y * 256;
  const int r = tid >> 1;          // token row 0..127
  const int g = tid & 1;           // which 64-group of the 128-k chunk
  const int srow2 = tid >> 2;      // A-store: row 0..63 (+64)
  const int scol2 = (tid & 3) * 8; // A-store: col

  f32x4 acc[2][2] = {};

  for (int c = 0; c < 2; ++c) {
    const int kbase = kc0 + c * 128;
    const int kcol  = g * 64;
    const float4* xp = (const float4*)&x[(size_t)(tok0 + r) * Kdim + kbase + kcol];
    const float4* sp = (const float4*)&smooth[kbase + kcol];
    float4 v[16];
#pragma unroll
    for (int q = 0; q < 16; ++q) {
      float4 xv = xp[q], sm = sp[q];
      v[q].x = xv.x * sm.x; v[q].y = xv.y * sm.y;
      v[q].z = xv.z * sm.z; v[q].w = xv.w * sm.w;
    }
    float a = 0.f;
#pragma unroll
    for (int q = 0; q < 16; ++q)
      a = fmaxf(a, fmaxf(fmaxf(fabsf(v[q].x), fabsf(v[q].y)),
                         fmaxf(fabsf(v[q].z), fabsf(v[q].w))));
    const float s = fmaxf(a / 7.0f, 1e-8f);   // exact div: must match np
#pragma unroll
    for (int q2 = 0; q2 < 8; ++q2) {
      const float4 v0 = v[2 * q2], v1 = v[2 * q2 + 1];
      uint4 wx, wq;
      wx.x = pack2(v0.x, v0.y);           wx.y = pack2(v0.z, v0.w);
      wx.z = pack2(v1.x, v1.y);           wx.w = pack2(v1.z, v1.w);
      wq.x = pack2(qd(v0.x, s), qd(v0.y, s)); wq.y = pack2(qd(v0.z, s), qd(v0.w, s));
      wq.z = pack2(qd(v1.x, s), qd(v1.y, s)); wq.w = pack2(qd(v1.z, s), qd(v1.w, s));
      *(uint4*)&sXS[r * 136 + kcol + q2 * 8] = wx;
      *(uint4*)&sQ [r * 136 + kcol + q2 * 8] = wq;
    }
    __syncthreads();

    // low-rank MFMA: t_partial += xs_tile @ pdT_tile (B fragments via vec loads)
#pragma unroll
    for (int kk = 0; kk < 4; ++kk) {
      const int kglob = kbase + kk * 32 + fk;
      bf16x8 af0 = *(const bf16x8*)&sXS[(wave * 32 + fr) * 136 + kk * 32 + fk];
      bf16x8 af1 = *(const bf16x8*)&sXS[(wave * 32 + 16 + fr) * 136 + kk * 32 + fk];
      bf16x8 b0 = *(const bf16x8*)&pdT[(size_t)fr * Kdim + kglob];
      bf16x8 b1 = *(const bf16x8*)&pdT[(size_t)(16 + fr) * Kdim + kglob];
      acc[0][0] = __builtin_amdgcn_mfma_f32_16x16x32_bf16(af0, b0, acc[0][0], 0, 0, 0);
      acc[0][1] = __builtin_amdgcn_mfma_f32_16x16x32_bf16(af0, b1, acc[0][1], 0, 0, 0);
      acc[1][0] = __builtin_amdgcn_mfma_f32_16x16x32_bf16(af1, b0, acc[1][0], 0, 0, 0);
      acc[1][1] = __builtin_amdgcn_mfma_f32_16x16x32_bf16(af1, b1, acc[1][1], 0, 0, 0);
    }

    // coalesced A store from sQ
#pragma unroll
    for (int h = 0; h < 2; ++h) {
      const int rr = srow2 + h * 64;
#pragma unroll
      for (int u = 0; u < 4; ++u)
        *(uint4*)&A[(size_t)(tok0 + rr) * K2 + kbase + scol2 + u * 32] =
            *(const uint4*)&sQ[rr * 136 + scol2 + u * 32];
    }
    __syncthreads();
  }

  float* P = partials + (size_t)blockIdx.y * Tdim * 32;
#pragma unroll
  for (int i = 0; i < 2; ++i) {
    const int row0 = tok0 + wave * 32 + i * 16 + fkq * 4;
#pragma unroll
    for (int j = 0; j < 2; ++j) {
      const int col = j * 16 + fr;
#pragma unroll
      for (int rr = 0; rr < 4; ++rr)
        P[(size_t)(row0 + rr) * 32 + col] = acc[i][j][rr];
    }
  }
}

// ====== K2: weight dequant (bid<8192) | A-tail reduce (8192..9215) | B-tail ==
__global__ __launch_bounds__(256) void wprep_kernel(
    const int* __restrict__ qw, const float* __restrict__ wsc,
    const float* __restrict__ partials, const float* __restrict__ pu,
    ushort* __restrict__ A, ushort* __restrict__ B) {
  const int bid = blockIdx.x;
  if (bid < 8192) {
    // dequantize int4 weights -> B' bf16, 8 elems/thread
    const size_t idx = ((size_t)bid * 256 + threadIdx.x) * 8;
    const int n = (int)(idx >> 12);
    const int k = (int)(idx & 4095);
    const float s = wsc[n * 64 + (k >> 6)];
    const int4 q0 = *(const int4*)(qw + idx);
    const int4 q1 = *(const int4*)(qw + idx + 4);
    uint4 o;
    o.x = pack2((float)q0.x * s, (float)q0.y * s);
    o.y = pack2((float)q0.z * s, (float)q0.w * s);
    o.z = pack2((float)q1.x * s, (float)q1.y * s);
    o.w = pack2((float)q1.z * s, (float)q1.w * s);
    *(uint4*)(B + (size_t)n * K2 + k) = o;
  } else if (bid < 8192 + 1024) {
    // reduce K-split partials -> bf16 into A tail cols [4096..4160)
    const int idx = (bid - 8192) * 256 + threadIdx.x;   // T*64 threads
    const int token = idx >> 6, c = idx & 63;
    ushort v = 0;
    if (c < 32) {
      float s = 0.f;
#pragma unroll
      for (int p = 0; p < NSPLIT; ++p)
        s += partials[(size_t)p * Tdim * 32 + (size_t)token * 32 + c];
      v = f2bf(s);
    }
    A[(size_t)token * K2 + Kdim + c] = v;
  } else {
    // B tail cols = [bf16(pu^T) | zeros]
    const int idx = (bid - 9216) * 256 + threadIdx.x;   // N*64 threads
    const int n = idx >> 6, c = idx & 63;
    ushort v = 0;
    if (c < 32) v = f2bf(pu[(size_t)c * Ndim + n]);     // proj_up is [32, N]
    B[(size_t)n * K2 + Kdim + c] = v;
  }
}

// ========== K3: C = A' @ B'^T + bias ========================================
// 256x256 tile, 8 waves (2M x 4N), BK=32 K-steps, ring-3 LDS slots per operand
// (96 KB total), stage-2-ahead. ONE barrier per K-step: with ring-3 the only
// hazards are (a) WAR on STAGE(s+2) vs reads of slot(s-1) -- those reads are
// lgkm-complete before barrier B_{s-1} since the MFMAs consumed them; (b) RAW
// on reads of slot(s+1) -- covered by per-wave vmcnt(4) before B_s. Inside a
// step: issue phase-A reads (8), staging, phase-B reads (4), then both MFMA
// bursts. Compiler's fine-grained lgkmcnt lets phase-A MFMAs start while
// phase-B reads are in flight; waves de-lockstep so LDS traffic hides under
// the MFMA pipe instead of serializing with it (the round-1 39% MfmaUtil
// ceiling was exactly this serialization). sched_barrier(0) pins the reads
// above the MFMA cluster. LDS chunk-XOR swizzle via pre-swizzled global
// source (rule #21) kept unchanged -> 0 bank conflicts.
__global__ __launch_bounds__(512, 2) void gemm_kernel(
    const ushort* __restrict__ A, const ushort* __restrict__ B,
    const float* __restrict__ bias, float* __restrict__ C) {
  __shared__ __attribute__((aligned(16))) ushort sA[3 * 8192];  // 48 KB
  __shared__ __attribute__((aligned(16))) ushort sB[3 * 8192];  // 48 KB
  const int tid  = threadIdx.x;
  const int lane = tid & 63;
  const int wave = tid >> 6;
  const int wm = wave >> 2;            // 0..1: which 128-row half
  const int wn = wave & 3;             // 0..3: which 64-col quarter
  const int fr  = lane & 15;
  const int fkq = lane >> 4;           // 0..3: k-chunk of the fragment
  const int fchunk = (fkq ^ ((fr >> 1) & 3)) * 8;   // un-swizzled read chunk

  // XCD-chunked block swizzle: XCD x (= bid & 7) owns a 4x8 rectangle of the
  // 16x16 block grid (256 blocks, nwg % 8 == 0 -> bijective).
  const int bid  = blockIdx.x;
  const int xcd  = bid & 7;
  const int i0   = bid >> 3;           // 0..31 within XCD
  const int brow = (xcd >> 1) * 4 + (i0 >> 3);
  const int bcol = (xcd & 1) * 8 + (i0 & 7);
  const size_t arow0 = (size_t)brow * 256;
  const size_t brow0 = (size_t)bcol * 256;

  // staging: thread fills LDS rows tid>>2 and tid>>2+128, chunk tid&3;
  // source column chunk is pre-swizzled so LDS dest is linear.
  const int srow = tid >> 2;                            // 0..127
  const int swz  = ((tid & 3) ^ ((tid >> 3) & 3)) * 8;  // source chunk
  const ushort* gA = A + (arow0 + srow) * K2 + swz;
  const ushort* gB = B + (brow0 + srow) * K2 + swz;

  const int rbase = wm * 128;    // wave's row base within the 256-row tile
  const int cbase = wn * 64;     // wave's col base within the 256-col tile

  f32x4 acc[8][4] = {};

#define MF(i, j, a, b) \
  acc[i][j] = __builtin_amdgcn_mfma_f32_16x16x32_bf16(a, b, acc[i][j], 0, 0, 0)
#define STAGE_A(st, so) \
  { async16(gA + (size_t)(st) * 32,                    &sA[(so) + tid * 8]);         \
    async16(gA + (size_t)(st) * 32 + (size_t)128 * K2, &sA[(so) + (tid + 512) * 8]); }
#define STAGE_B(st, so) \
  { async16(gB + (size_t)(st) * 32,                    &sB[(so) + tid * 8]);         \
    async16(gB + (size_t)(st) * 32 + (size_t)128 * K2, &sB[(so) + (tid + 512) * 8]); }
#define FENCE() asm volatile("" ::: "memory")
#define BARRIER() { FENCE(); __builtin_amdgcn_s_barrier(); FENCE(); }

  // ---- prologue: stage K-steps 0 and 1 (slots 0,1); wait for step 0 ----
  STAGE_A(0, 0); STAGE_B(0, 0);
  STAGE_A(1, 8192); STAGE_B(1, 8192);
  asm volatile("s_waitcnt vmcnt(4)" ::: "memory");   // step 0 landed
  BARRIER();

  for (int s = 0; s < NT; ++s) {
    const int sl  = (s % 3) * 8192;
    const int sn  = s + 2;
    const int sln = (sn % 3) * 8192;
    const ushort* al = &sA[sl];
    const ushort* bl = &sB[sl];

    // R1: phase-A fragments (8 x ds_read_b128)
    bf16x8 af0 = *(const bf16x8*)&al[(rbase +  0 + fr) * 32 + fchunk];
    bf16x8 af1 = *(const bf16x8*)&al[(rbase + 16 + fr) * 32 + fchunk];
    bf16x8 af2 = *(const bf16x8*)&al[(rbase + 32 + fr) * 32 + fchunk];
    bf16x8 af3 = *(const bf16x8*)&al[(rbase + 48 + fr) * 32 + fchunk];
    bf16x8 bf0 = *(const bf16x8*)&bl[(cbase +  0 + fr) * 32 + fchunk];
    bf16x8 bf1 = *(const bf16x8*)&bl[(cbase + 16 + fr) * 32 + fchunk];
    bf16x8 bf2 = *(const bf16x8*)&bl[(cbase + 32 + fr) * 32 + fchunk];
    bf16x8 bf3 = *(const bf16x8*)&bl[(cbase + 48 + fr) * 32 + fchunk];

    // S: prefetch K-step s+2 (WAR-safe: slot(s+2)==slot(s-1), whose reads
    // completed before B_{s-1})
    if (sn < NT) { STAGE_A(sn, sln); STAGE_B(sn, sln); }

    // R2: phase-B A-fragments (4 x ds_read_b128) -- overlap the M1 burst
    bf16x8 ag0 = *(const bf16x8*)&al[(rbase +  64 + fr) * 32 + fchunk];
    bf16x8 ag1 = *(const bf16x8*)&al[(rbase +  80 + fr) * 32 + fchunk];
    bf16x8 ag2 = *(const bf16x8*)&al[(rbase +  96 + fr) * 32 + fchunk];
    bf16x8 ag3 = *(const bf16x8*)&al[(rbase + 112 + fr) * 32 + fchunk];
    __builtin_amdgcn_sched_barrier(0);   // pin reads above the MFMA cluster

    // M1: rows 0..63 x all cols (waits lgkm for R1 only; R2 stays in flight)
    __builtin_amdgcn_s_setprio(1);
    MF(0, 0, af0, bf0); MF(1, 0, af1, bf0); MF(2, 0, af2, bf0); MF(3, 0, af3, bf0);
    MF(0, 1, af0, bf1); MF(1, 1, af1, bf1); MF(2, 1, af2, bf1); MF(3, 1, af3, bf1);
    MF(0, 2, af0, bf2); MF(1, 2, af1, bf2); MF(2, 2, af2, bf2); MF(3, 2, af3, bf2);
    MF(0, 3, af0, bf3); MF(1, 3, af1, bf3); MF(2, 3, af2, bf3); MF(3, 3, af3, bf3);

    // M2: rows 64..127 (B-frags reused)
    MF(4, 0, ag0, bf0); MF(5, 0, ag1, bf0); MF(6, 0, ag2, bf0); MF(7, 0, ag3, bf0);
    MF(4, 1, ag0, bf1); MF(5, 1, ag1, bf1); MF(6, 1, ag2, bf1); MF(7, 1, ag3, bf1);
    MF(4, 2, ag0, bf2); MF(5, 2, ag1, bf2); MF(6, 2, ag2, bf2); MF(7, 2, ag3, bf2);
    MF(4, 3, ag0, bf3); MF(5, 3, ag1, bf3); MF(6, 3, ag2, bf3); MF(7, 3, ag3, bf3);
    __builtin_amdgcn_s_setprio(0);

    // one wait + one barrier per K-step: my s+1 loads landed (issued a full
    // step ago); after the barrier every wave's s+1 loads have landed and all
    // reads of slot(s) are complete chip-wide.
    if (s < NT - 2)       asm volatile("s_waitcnt vmcnt(4)" ::: "memory");
    else if (s == NT - 2) asm volatile("s_waitcnt vmcnt(0)" ::: "memory");
    BARRIER();
  }
#undef MF
#undef STAGE_A
#undef STAGE_B
#undef FENCE
#undef BARRIER

  // ---- epilogue: C = acc + bias (same C/D layout as before) ----
#pragma unroll
  for (int j = 0; j < 4; ++j) {
    const size_t col = brow0 + cbase + j * 16 + fr;
    const float bv = bias[col];
#pragma unroll
    for (int i = 0; i < 8; ++i) {
      const size_t row = arow0 + rbase + i * 16 + fkq * 4;
#pragma unroll
      for (int r = 0; r < 4; ++r)
        C[(row + r) * Ndim + col] = acc[i][j][r] + bv;
    }
  }
}

extern "C" void kernel_launch(void* const* d_in, const int* in_sizes, int n_in,
                              void* d_out, int out_size, void* d_ws, size_t ws_size,
                              hipStream_t stream) {
  const float* x      = (const float*)d_in[0];
  const int*   qw     = (const int*)d_in[1];
  const float* wsc    = (const float*)d_in[2];
  const float* pd     = (const float*)d_in[3];
  const float* pu     = (const float*)d_in[4];
  const float* smooth = (const float*)d_in[5];
  const float* bias   = (const float*)d_in[6];
  float* out = (float*)d_out;

  const size_t abytes = (size_t)Tdim * K2 * 2;          // 34,078,720
  ushort* A    = (ushort*)d_ws;
  ushort* B    = (ushort*)((char*)d_ws + abytes);
  ushort* pdT  = (ushort*)((char*)d_ws + 2 * abytes);   // 32*4096*2 = 256 KB
  float*  part = (float*)((char*)d_ws + 2 * abytes + 262144);  // 16*T*32*4 = 8 MB

  hipLaunchKernelGGL(prep_pdT_kernel, dim3(512),    dim3(256), 0, stream, pd, pdT);
  hipLaunchKernelGGL(prep_a_kernel,   dim3(32, NSPLIT), dim3(256), 0, stream, x, smooth, pdT, A, part);
  hipLaunchKernelGGL(wprep_kernel,    dim3(10240),  dim3(256), 0, stream, qw, wsc, part, pu, A, B);
  hipLaunchKernelGGL(gemm_kernel,     dim3(256),    dim3(512), 0, stream, A, B, bias, out);
}

// Round 3
// 336.228 us; speedup vs baseline: 1.0497x; 1.0497x over previous
//
#include <hip/hip_runtime.h>
#include <hip/hip_bf16.h>
#include <stdint.h>

#define Tdim 4096
#define Ndim 4096
#define Kdim 4096
#define K2   4160   // 4096 + 32 (low-rank concat) + 32 (zero pad to multiple of 64)
#define NSPLIT 16   // K-splits for the low-rank partial GEMM
#define NT64 65     // K2 / 64 K-tiles for the main GEMM

using f32x4  = __attribute__((ext_vector_type(4))) float;
using bf16x8 = __attribute__((ext_vector_type(8))) short;

// round-to-nearest-even f32 -> bf16 bits
__device__ inline ushort f2bf(float f) {
  union { float f; unsigned u; } v; v.f = f;
  unsigned lsb = (v.u >> 16) & 1u;
  v.u += 0x7fffu + lsb;
  return (ushort)(v.u >> 16);
}

__device__ inline unsigned pack2(float a, float b) {
  return (unsigned)f2bf(a) | ((unsigned)f2bf(b) << 16);
}

__device__ inline float qd(float v, float s) {   // quantize-dequantize
  return fminf(fmaxf(rintf(v / s), -8.f), 7.f) * s;
}

__device__ inline void async16(const void* g, void* l) {
  __builtin_amdgcn_global_load_lds(
      (const __attribute__((address_space(1))) unsigned int*)g,
      (__attribute__((address_space(3))) unsigned int*)l, 16, 0, 0);
}

// ---------------- K0: pdT[n][k] = bf16(pd[k][n])  (32 x 4096) ---------------
__global__ __launch_bounds__(256) void prep_pdT_kernel(
    const float* __restrict__ pd, ushort* __restrict__ pdT) {
  const int idx = blockIdx.x * 256 + threadIdx.x;   // 32*4096 threads
  const int n = idx >> 12;
  const int k = idx & 4095;
  pdT[(size_t)n * Kdim + k] = f2bf(pd[(size_t)k * 32 + n]);
}

// ========== K1: fused activation quant-dequant + low-rank partial GEMM ======
// grid (32 token-tiles, 16 k-splits); block covers 128 tokens x 256 k.
// Writes A[token][0..4095] (bf16 qdq values) and partials[split][T][32].
__global__ __launch_bounds__(256) void prep_a_kernel(
    const float* __restrict__ x, const float* __restrict__ smooth,
    const ushort* __restrict__ pdT, ushort* __restrict__ A,
    float* __restrict__ partials) {
  __shared__ __attribute__((aligned(16))) ushort sXS[128 * 136];  // xs (bf16) for MFMA
  __shared__ __attribute__((aligned(16))) ushort sQ[128 * 136];   // qdq(xs) for A
  const int tid  = threadIdx.x;
  const int lane = tid & 63;
  const int wave = tid >> 6;
  const int fr  = lane & 15;
  const int fkq = lane >> 4;
  const int fk  = fkq * 8;
  const int tok0 = blockIdx.x * 128;
  const int kc0  = blockIdx.y * 256;
  const int r = tid >> 1;          // token row 0..127
  const int g = tid & 1;           // which 64-group of the 128-k chunk
  const int srow2 = tid >> 2;      // A-store: row 0..63 (+64)
  const int scol2 = (tid & 3) * 8; // A-store: col

  f32x4 acc[2][2] = {};

  for (int c = 0; c < 2; ++c) {
    const int kbase = kc0 + c * 128;
    const int kcol  = g * 64;
    const float4* xp = (const float4*)&x[(size_t)(tok0 + r) * Kdim + kbase + kcol];
    const float4* sp = (const float4*)&smooth[kbase + kcol];
    float4 v[16];
#pragma unroll
    for (int q = 0; q < 16; ++q) {
      float4 xv = xp[q], sm = sp[q];
      v[q].x = xv.x * sm.x; v[q].y = xv.y * sm.y;
      v[q].z = xv.z * sm.z; v[q].w = xv.w * sm.w;
    }
    float a = 0.f;
#pragma unroll
    for (int q = 0; q < 16; ++q)
      a = fmaxf(a, fmaxf(fmaxf(fabsf(v[q].x), fabsf(v[q].y)),
                         fmaxf(fabsf(v[q].z), fabsf(v[q].w))));
    const float s = fmaxf(a / 7.0f, 1e-8f);   // exact div: must match np
#pragma unroll
    for (int q2 = 0; q2 < 8; ++q2) {
      const float4 v0 = v[2 * q2], v1 = v[2 * q2 + 1];
      uint4 wx, wq;
      wx.x = pack2(v0.x, v0.y);           wx.y = pack2(v0.z, v0.w);
      wx.z = pack2(v1.x, v1.y);           wx.w = pack2(v1.z, v1.w);
      wq.x = pack2(qd(v0.x, s), qd(v0.y, s)); wq.y = pack2(qd(v0.z, s), qd(v0.w, s));
      wq.z = pack2(qd(v1.x, s), qd(v1.y, s)); wq.w = pack2(qd(v1.z, s), qd(v1.w, s));
      *(uint4*)&sXS[r * 136 + kcol + q2 * 8] = wx;
      *(uint4*)&sQ [r * 136 + kcol + q2 * 8] = wq;
    }
    __syncthreads();

    // low-rank MFMA: t_partial += xs_tile @ pdT_tile (B fragments via vec loads)
#pragma unroll
    for (int kk = 0; kk < 4; ++kk) {
      const int kglob = kbase + kk * 32 + fk;
      bf16x8 af0 = *(const bf16x8*)&sXS[(wave * 32 + fr) * 136 + kk * 32 + fk];
      bf16x8 af1 = *(const bf16x8*)&sXS[(wave * 32 + 16 + fr) * 136 + kk * 32 + fk];
      bf16x8 b0 = *(const bf16x8*)&pdT[(size_t)fr * Kdim + kglob];
      bf16x8 b1 = *(const bf16x8*)&pdT[(size_t)(16 + fr) * Kdim + kglob];
      acc[0][0] = __builtin_amdgcn_mfma_f32_16x16x32_bf16(af0, b0, acc[0][0], 0, 0, 0);
      acc[0][1] = __builtin_amdgcn_mfma_f32_16x16x32_bf16(af0, b1, acc[0][1], 0, 0, 0);
      acc[1][0] = __builtin_amdgcn_mfma_f32_16x16x32_bf16(af1, b0, acc[1][0], 0, 0, 0);
      acc[1][1] = __builtin_amdgcn_mfma_f32_16x16x32_bf16(af1, b1, acc[1][1], 0, 0, 0);
    }

    // coalesced A store from sQ
#pragma unroll
    for (int h = 0; h < 2; ++h) {
      const int rr = srow2 + h * 64;
#pragma unroll
      for (int u = 0; u < 4; ++u)
        *(uint4*)&A[(size_t)(tok0 + rr) * K2 + kbase + scol2 + u * 32] =
            *(const uint4*)&sQ[rr * 136 + scol2 + u * 32];
    }
    __syncthreads();
  }

  float* P = partials + (size_t)blockIdx.y * Tdim * 32;
#pragma unroll
  for (int i = 0; i < 2; ++i) {
    const int row0 = tok0 + wave * 32 + i * 16 + fkq * 4;
#pragma unroll
    for (int j = 0; j < 2; ++j) {
      const int col = j * 16 + fr;
#pragma unroll
      for (int rr = 0; rr < 4; ++rr)
        P[(size_t)(row0 + rr) * 32 + col] = acc[i][j][rr];
    }
  }
}

// ====== K2: weight dequant (bid<8192) | A-tail reduce (8192..9215) | B-tail ==
__global__ __launch_bounds__(256) void wprep_kernel(
    const int* __restrict__ qw, const float* __restrict__ wsc,
    const float* __restrict__ partials, const float* __restrict__ pu,
    ushort* __restrict__ A, ushort* __restrict__ B) {
  const int bid = blockIdx.x;
  if (bid < 8192) {
    // dequantize int4 weights -> B' bf16, 8 elems/thread
    const size_t idx = ((size_t)bid * 256 + threadIdx.x) * 8;
    const int n = (int)(idx >> 12);
    const int k = (int)(idx & 4095);
    const float s = wsc[n * 64 + (k >> 6)];
    const int4 q0 = *(const int4*)(qw + idx);
    const int4 q1 = *(const int4*)(qw + idx + 4);
    uint4 o;
    o.x = pack2((float)q0.x * s, (float)q0.y * s);
    o.y = pack2((float)q0.z * s, (float)q0.w * s);
    o.z = pack2((float)q1.x * s, (float)q1.y * s);
    o.w = pack2((float)q1.z * s, (float)q1.w * s);
    *(uint4*)(B + (size_t)n * K2 + k) = o;
  } else if (bid < 8192 + 1024) {
    // reduce K-split partials -> bf16 into A tail cols [4096..4160)
    const int idx = (bid - 8192) * 256 + threadIdx.x;   // T*64 threads
    const int token = idx >> 6, c = idx & 63;
    ushort v = 0;
    if (c < 32) {
      float s = 0.f;
#pragma unroll
      for (int p = 0; p < NSPLIT; ++p)
        s += partials[(size_t)p * Tdim * 32 + (size_t)token * 32 + c];
      v = f2bf(s);
    }
    A[(size_t)token * K2 + Kdim + c] = v;
  } else {
    // B tail cols = [bf16(pu^T) | zeros]
    const int idx = (bid - 9216) * 256 + threadIdx.x;   // N*64 threads
    const int n = idx >> 6, c = idx & 63;
    ushort v = 0;
    if (c < 32) v = f2bf(pu[(size_t)c * Ndim + n]);     // proj_up is [32, N]
    B[(size_t)n * K2 + Kdim + c] = v;
  }
}

// ========== K3: C = A' @ B'^T + bias  (m201 8-phase template port) ==========
// 256x256 tile, 8 waves (2M x 4N), BK=64 K-tiles, 2-slot LDS double-buffer
// ([2][256][64] bf16 per operand = 128 KB). Per K-tile: 4 quadrant-phases,
// each {ds_read subtile (12/8/4/0, frag reuse in regs); barrier; lgkmcnt(0)
// + sched_barrier (rule 18); setprio(1); 16 MFMA; setprio(0); barrier}.
// All 8 stage-instrs for tile t+1 issue in t's phase 1 (WAR-safe: slot(t+1)
// = slot(t-1), whose reads were lgkm-drained before t-1's last MFMA burst,
// hence before t's phase-1 issue). Boundary s_waitcnt vmcnt(0) at end of
// phase 4 waits on loads >=3 phases (~1500 cyc) old -> no fresh-load stall
// (the m218 counted-vmcnt property, achieved by age instead of N). LDS
// chunk-XOR swizzle c' = c ^ (row&7) over the 8 16B-chunks of a 128B row,
// applied via pre-swizzled global source (rule 21): conflict-free
// ds_read_b128 (each chunk-group gets exactly 8 of 64 lanes).
__global__ __launch_bounds__(512, 2) void gemm_kernel(
    const ushort* __restrict__ A, const ushort* __restrict__ B,
    const float* __restrict__ bias, float* __restrict__ C) {
  __shared__ __attribute__((aligned(16))) ushort sA[2 * 16384];  // 64 KB
  __shared__ __attribute__((aligned(16))) ushort sB[2 * 16384];  // 64 KB
  const int tid  = threadIdx.x;
  const int lane = tid & 63;
  const int wave = tid >> 6;
  const int wm = wave >> 2;            // 0..1: which 128-row half
  const int wn = wave & 3;             // 0..3: which 64-col quarter
  const int fr  = lane & 15;
  const int fkq = lane >> 4;           // 0..3: 16B chunk within a 32-k group
  // swizzled read chunks for kk=0,1: global chunk kk*4+fkq, XOR row&7 (=fr&7)
  const int c0 = ((fkq    ) ^ (fr & 7)) * 8;
  const int c1 = ((fkq + 4) ^ (fr & 7)) * 8;

  // XCD-chunked block swizzle: XCD x (= bid & 7) owns a 4x8 rectangle of the
  // 16x16 block grid (256 blocks, nwg % 8 == 0 -> bijective).
  const int bid  = blockIdx.x;
  const int xcd  = bid & 7;
  const int i0   = bid >> 3;           // 0..31 within XCD
  const int brow = (xcd >> 1) * 4 + (i0 >> 3);
  const int bcol = (xcd & 1) * 8 + (i0 & 7);
  const size_t arow0 = (size_t)brow * 256;
  const size_t brow0 = (size_t)bcol * 256;

  // staging: thread tid fills LDS rows {0,64,128,192}+ (tid>>3), chunk tid&7;
  // LDS dest linear in tid (global_load_lds constraint); source column chunk
  // pre-swizzled by ^(row&7) = ^((tid>>3)&7).
  const int srow = tid >> 3;                            // 0..63
  const int swz  = ((tid & 7) ^ (srow & 7)) * 8;        // source chunk (elems)
  const ushort* gA = A + (arow0 + srow) * K2 + swz;
  const ushort* gB = B + (brow0 + srow) * K2 + swz;

  f32x4 acc[8][4] = {};

#define STAGE8(T)                                                            \
  do {                                                                       \
    const size_t tk = (size_t)(T) * 64;                                      \
    const int so = (((T) & 1) * 16384) + tid * 8;                            \
    async16(gA + tk,                     &sA[so]);                           \
    async16(gA + tk + (size_t)64  * K2,  &sA[so + 4096]);                    \
    async16(gA + tk + (size_t)128 * K2,  &sA[so + 8192]);                    \
    async16(gA + tk + (size_t)192 * K2,  &sA[so + 12288]);                   \
    async16(gB + tk,                     &sB[so]);                           \
    async16(gB + tk + (size_t)64  * K2,  &sB[so + 4096]);                    \
    async16(gB + tk + (size_t)128 * K2,  &sB[so + 8192]);                    \
    async16(gB + tk + (size_t)192 * K2,  &sB[so + 12288]);                   \
  } while (0)
#define LDA(DST, ROFF)                                                       \
  do {                                                                       \
    _Pragma("unroll") for (int ii = 0; ii < 4; ++ii) {                       \
      DST[ii][0] = *(const bf16x8*)&an[((ROFF) + ii * 16) * 64 + c0];        \
      DST[ii][1] = *(const bf16x8*)&an[((ROFF) + ii * 16) * 64 + c1];        \
    }                                                                        \
  } while (0)
#define LDB(DST, ROFF)                                                       \
  do {                                                                       \
    _Pragma("unroll") for (int jj = 0; jj < 2; ++jj) {                       \
      DST[jj][0] = *(const bf16x8*)&bn[((ROFF) + jj * 16) * 64 + c0];        \
      DST[jj][1] = *(const bf16x8*)&bn[((ROFF) + jj * 16) * 64 + c1];        \
    }                                                                        \
  } while (0)
#define MFMA16(RB, CB, AF, BF)                                               \
  do {                                                                       \
    __builtin_amdgcn_s_setprio(1);                                           \
    _Pragma("unroll") for (int kk = 0; kk < 2; ++kk)                         \
      _Pragma("unroll") for (int jj = 0; jj < 2; ++jj)                       \
        _Pragma("unroll") for (int ii = 0; ii < 4; ++ii)                     \
          acc[(RB) + ii][(CB) + jj] =                                        \
              __builtin_amdgcn_mfma_f32_16x16x32_bf16(                       \
                  AF[ii][kk], BF[jj][kk], acc[(RB) + ii][(CB) + jj], 0, 0, 0); \
    __builtin_amdgcn_s_setprio(0);                                           \
  } while (0)
#define FENCE() asm volatile("" ::: "memory")
#define BARRIER() { FENCE(); __builtin_amdgcn_s_barrier(); FENCE(); }
#define LGKM0()                                                              \
  { asm volatile("s_waitcnt lgkmcnt(0)" ::: "memory");                       \
    __builtin_amdgcn_sched_barrier(0); }

  // ---- prologue: stage K-tile 0 into slot 0 ----
  STAGE8(0);
  asm volatile("s_waitcnt vmcnt(0)" ::: "memory");
  BARRIER();

  for (int t = 0; t < NT64; ++t) {
    const int sl = (t & 1) * 16384;
    const ushort* an = &sA[sl + (wm * 128 + fr) * 64];
    const ushort* bn = &sB[sl + (wn * 64 + fr) * 64];
    bf16x8 A0f[4][2], A1f[4][2], B0f[2][2], B1f[2][2];

    // ---- phase 1: quadrant (0,0).  12 ds_reads + all 8 stage-instrs ----
    LDA(A0f, 0);
    LDB(B0f, 0);
    if (t + 1 < NT64) STAGE8(t + 1);
    asm volatile("s_waitcnt lgkmcnt(8)" ::: "memory");  // pre-drain 4 of 12
    __builtin_amdgcn_sched_barrier(0);
    BARRIER();
    LGKM0();
    MFMA16(0, 0, A0f, B0f);
    BARRIER();

    // ---- phase 2: quadrant (1,0).  8 ds_reads (B0 reused) ----
    LDA(A1f, 64);
    BARRIER();
    LGKM0();
    MFMA16(4, 0, A1f, B0f);
    BARRIER();

    // ---- phase 3: quadrant (1,1).  4 ds_reads (A1 reused) ----
    LDB(B1f, 32);
    BARRIER();
    LGKM0();
    MFMA16(4, 2, A1f, B1f);
    BARRIER();

    // ---- phase 4: quadrant (0,1).  0 ds_reads (A0, B1 reused) ----
    MFMA16(0, 2, A0f, B1f);
    // boundary wait: tile t+1's loads (issued in phase 1, ~3 phases old)
    if (t + 1 < NT64) asm volatile("s_waitcnt vmcnt(0)" ::: "memory");
    BARRIER();
  }
#undef STAGE8
#undef LDA
#undef LDB
#undef MFMA16
#undef FENCE
#undef BARRIER
#undef LGKM0

  // ---- epilogue: C = acc + bias (same C/D layout as before) ----
  const int rbase = wm * 128;
  const int cbase = wn * 64;
#pragma unroll
  for (int j = 0; j < 4; ++j) {
    const size_t col = brow0 + cbase + j * 16 + fr;
    const float bv = bias[col];
#pragma unroll
    for (int i = 0; i < 8; ++i) {
      const size_t row = arow0 + rbase + i * 16 + fkq * 4;
#pragma unroll
      for (int r = 0; r < 4; ++r)
        C[(row + r) * Ndim + col] = acc[i][j][r] + bv;
    }
  }
}

extern "C" void kernel_launch(void* const* d_in, const int* in_sizes, int n_in,
                              void* d_out, int out_size, void* d_ws, size_t ws_size,
                              hipStream_t stream) {
  const float* x      = (const float*)d_in[0];
  const int*   qw     = (const int*)d_in[1];
  const float* wsc    = (const float*)d_in[2];
  const float* pd     = (const float*)d_in[3];
  const float* pu     = (const float*)d_in[4];
  const float* smooth = (const float*)d_in[5];
  const float* bias   = (const float*)d_in[6];
  float* out = (float*)d_out;

  const size_t abytes = (size_t)Tdim * K2 * 2;          // 34,078,720
  ushort* A    = (ushort*)d_ws;
  ushort* B    = (ushort*)((char*)d_ws + abytes);
  ushort* pdT  = (ushort*)((char*)d_ws + 2 * abytes);   // 32*4096*2 = 256 KB
  float*  part = (float*)((char*)d_ws + 2 * abytes + 262144);  // 16*T*32*4 = 8 MB

  hipLaunchKernelGGL(prep_pdT_kernel, dim3(512),    dim3(256), 0, stream, pd, pdT);
  hipLaunchKernelGGL(prep_a_kernel,   dim3(32, NSPLIT), dim3(256), 0, stream, x, smooth, pdT, A, part);
  hipLaunchKernelGGL(wprep_kernel,    dim3(10240),  dim3(256), 0, stream, qw, wsc, part, pu, A, B);
  hipLaunchKernelGGL(gemm_kernel,     dim3(256),    dim3(512), 0, stream, A, B, bias, out);
}

// Round 4
// 336.086 us; speedup vs baseline: 1.0502x; 1.0004x over previous
//
#include <hip/hip_runtime.h>
#include <hip/hip_bf16.h>
#include <stdint.h>

#define Tdim 4096
#define Ndim 4096
#define Kdim 4096
#define K2   4160   // 4096 + 32 (low-rank concat) + 32 (zero pad to multiple of 64)
#define NSPLIT 16   // K-splits for the low-rank partial GEMM
#define NT   130    // K2 / 32 K-steps for the main GEMM

using f32x4  = __attribute__((ext_vector_type(4))) float;
using bf16x8 = __attribute__((ext_vector_type(8))) short;

// round-to-nearest-even f32 -> bf16 bits
__device__ inline ushort f2bf(float f) {
  union { float f; unsigned u; } v; v.f = f;
  unsigned lsb = (v.u >> 16) & 1u;
  v.u += 0x7fffu + lsb;
  return (ushort)(v.u >> 16);
}

__device__ inline unsigned pack2(float a, float b) {
  return (unsigned)f2bf(a) | ((unsigned)f2bf(b) << 16);
}

__device__ inline float qd(float v, float s) {   // quantize-dequantize
  return fminf(fmaxf(rintf(v / s), -8.f), 7.f) * s;
}

__device__ inline void async16(const void* g, void* l) {
  __builtin_amdgcn_global_load_lds(
      (const __attribute__((address_space(1))) unsigned int*)g,
      (__attribute__((address_space(3))) unsigned int*)l, 16, 0, 0);
}

// ---------------- K0: pdT[n][k] = bf16(pd[k][n])  (32 x 4096) ---------------
__global__ __launch_bounds__(256) void prep_pdT_kernel(
    const float* __restrict__ pd, ushort* __restrict__ pdT) {
  const int idx = blockIdx.x * 256 + threadIdx.x;   // 32*4096 threads
  const int n = idx >> 12;
  const int k = idx & 4095;
  pdT[(size_t)n * Kdim + k] = f2bf(pd[(size_t)k * 32 + n]);
}

// ========== K1: fused activation quant-dequant + low-rank partial GEMM ======
// grid (32 token-tiles, 16 k-splits); block covers 128 tokens x 256 k.
// Writes A[token][0..4095] (bf16 qdq values) and partials[split][T][32].
__global__ __launch_bounds__(256) void prep_a_kernel(
    const float* __restrict__ x, const float* __restrict__ smooth,
    const ushort* __restrict__ pdT, ushort* __restrict__ A,
    float* __restrict__ partials) {
  __shared__ __attribute__((aligned(16))) ushort sXS[128 * 136];  // xs (bf16) for MFMA
  __shared__ __attribute__((aligned(16))) ushort sQ[128 * 136];   // qdq(xs) for A
  const int tid  = threadIdx.x;
  const int lane = tid & 63;
  const int wave = tid >> 6;
  const int fr  = lane & 15;
  const int fkq = lane >> 4;
  const int fk  = fkq * 8;
  const int tok0 = blockIdx.x * 128;
  const int kc0  = blockIdx.y * 256;
  const int r = tid >> 1;          // token row 0..127
  const int g = tid & 1;           // which 64-group of the 128-k chunk
  const int srow2 = tid >> 2;      // A-store: row 0..63 (+64)
  const int scol2 = (tid & 3) * 8; // A-store: col

  f32x4 acc[2][2] = {};

  for (int c = 0; c < 2; ++c) {
    const int kbase = kc0 + c * 128;
    const int kcol  = g * 64;
    const float4* xp = (const float4*)&x[(size_t)(tok0 + r) * Kdim + kbase + kcol];
    const float4* sp = (const float4*)&smooth[kbase + kcol];
    float4 v[16];
#pragma unroll
    for (int q = 0; q < 16; ++q) {
      float4 xv = xp[q], sm = sp[q];
      v[q].x = xv.x * sm.x; v[q].y = xv.y * sm.y;
      v[q].z = xv.z * sm.z; v[q].w = xv.w * sm.w;
    }
    float a = 0.f;
#pragma unroll
    for (int q = 0; q < 16; ++q)
      a = fmaxf(a, fmaxf(fmaxf(fabsf(v[q].x), fabsf(v[q].y)),
                         fmaxf(fabsf(v[q].z), fabsf(v[q].w))));
    const float s = fmaxf(a / 7.0f, 1e-8f);   // exact div: must match np
#pragma unroll
    for (int q2 = 0; q2 < 8; ++q2) {
      const float4 v0 = v[2 * q2], v1 = v[2 * q2 + 1];
      uint4 wx, wq;
      wx.x = pack2(v0.x, v0.y);           wx.y = pack2(v0.z, v0.w);
      wx.z = pack2(v1.x, v1.y);           wx.w = pack2(v1.z, v1.w);
      wq.x = pack2(qd(v0.x, s), qd(v0.y, s)); wq.y = pack2(qd(v0.z, s), qd(v0.w, s));
      wq.z = pack2(qd(v1.x, s), qd(v1.y, s)); wq.w = pack2(qd(v1.z, s), qd(v1.w, s));
      *(uint4*)&sXS[r * 136 + kcol + q2 * 8] = wx;
      *(uint4*)&sQ [r * 136 + kcol + q2 * 8] = wq;
    }
    __syncthreads();

    // low-rank MFMA: t_partial += xs_tile @ pdT_tile (B fragments via vec loads)
#pragma unroll
    for (int kk = 0; kk < 4; ++kk) {
      const int kglob = kbase + kk * 32 + fk;
      bf16x8 af0 = *(const bf16x8*)&sXS[(wave * 32 + fr) * 136 + kk * 32 + fk];
      bf16x8 af1 = *(const bf16x8*)&sXS[(wave * 32 + 16 + fr) * 136 + kk * 32 + fk];
      bf16x8 b0 = *(const bf16x8*)&pdT[(size_t)fr * Kdim + kglob];
      bf16x8 b1 = *(const bf16x8*)&pdT[(size_t)(16 + fr) * Kdim + kglob];
      acc[0][0] = __builtin_amdgcn_mfma_f32_16x16x32_bf16(af0, b0, acc[0][0], 0, 0, 0);
      acc[0][1] = __builtin_amdgcn_mfma_f32_16x16x32_bf16(af0, b1, acc[0][1], 0, 0, 0);
      acc[1][0] = __builtin_amdgcn_mfma_f32_16x16x32_bf16(af1, b0, acc[1][0], 0, 0, 0);
      acc[1][1] = __builtin_amdgcn_mfma_f32_16x16x32_bf16(af1, b1, acc[1][1], 0, 0, 0);
    }

    // coalesced A store from sQ
#pragma unroll
    for (int h = 0; h < 2; ++h) {
      const int rr = srow2 + h * 64;
#pragma unroll
      for (int u = 0; u < 4; ++u)
        *(uint4*)&A[(size_t)(tok0 + rr) * K2 + kbase + scol2 + u * 32] =
            *(const uint4*)&sQ[rr * 136 + scol2 + u * 32];
    }
    __syncthreads();
  }

  float* P = partials + (size_t)blockIdx.y * Tdim * 32;
#pragma unroll
  for (int i = 0; i < 2; ++i) {
    const int row0 = tok0 + wave * 32 + i * 16 + fkq * 4;
#pragma unroll
    for (int j = 0; j < 2; ++j) {
      const int col = j * 16 + fr;
#pragma unroll
      for (int rr = 0; rr < 4; ++rr)
        P[(size_t)(row0 + rr) * 32 + col] = acc[i][j][rr];
    }
  }
}

// ====== K2: weight dequant (bid<8192) | A-tail reduce (8192..9215) | B-tail ==
__global__ __launch_bounds__(256) void wprep_kernel(
    const int* __restrict__ qw, const float* __restrict__ wsc,
    const float* __restrict__ partials, const float* __restrict__ pu,
    ushort* __restrict__ A, ushort* __restrict__ B) {
  const int bid = blockIdx.x;
  if (bid < 8192) {
    // dequantize int4 weights -> B' bf16, 8 elems/thread
    const size_t idx = ((size_t)bid * 256 + threadIdx.x) * 8;
    const int n = (int)(idx >> 12);
    const int k = (int)(idx & 4095);
    const float s = wsc[n * 64 + (k >> 6)];
    const int4 q0 = *(const int4*)(qw + idx);
    const int4 q1 = *(const int4*)(qw + idx + 4);
    uint4 o;
    o.x = pack2((float)q0.x * s, (float)q0.y * s);
    o.y = pack2((float)q0.z * s, (float)q0.w * s);
    o.z = pack2((float)q1.x * s, (float)q1.y * s);
    o.w = pack2((float)q1.z * s, (float)q1.w * s);
    *(uint4*)(B + (size_t)n * K2 + k) = o;
  } else if (bid < 8192 + 1024) {
    // reduce K-split partials -> bf16 into A tail cols [4096..4160)
    const int idx = (bid - 8192) * 256 + threadIdx.x;   // T*64 threads
    const int token = idx >> 6, c = idx & 63;
    ushort v = 0;
    if (c < 32) {
      float s = 0.f;
#pragma unroll
      for (int p = 0; p < NSPLIT; ++p)
        s += partials[(size_t)p * Tdim * 32 + (size_t)token * 32 + c];
      v = f2bf(s);
    }
    A[(size_t)token * K2 + Kdim + c] = v;
  } else {
    // B tail cols = [bf16(pu^T) | zeros]
    const int idx = (bid - 9216) * 256 + threadIdx.x;   // N*64 threads
    const int n = idx >> 6, c = idx & 63;
    ushort v = 0;
    if (c < 32) v = f2bf(pu[(size_t)c * Ndim + n]);     // proj_up is [32, N]
    B[(size_t)n * K2 + Kdim + c] = v;
  }
}

// ========== K3: C = A' @ B'^T + bias  (read-ahead 2-phase pipeline) =========
// 256x256 tile, 8 waves (2M x 4N), BK=32, ring-3 LDS slots (96 KB), stage-2-
// ahead (round-1's proven vmcnt(4) ledger). KEY CHANGE vs rounds 1/3: the
// fragments consumed by phase p's MFMA cluster are read in phase p-1, so the
// compiler's auto-waitcnt before the MFMAs is a COUNTED lgkmcnt(4/8) on
// already-landed reads, and the fresh reads (for p+1) + the 4 stage instrs
// execute in the LDS/VMEM pipes UNDER the MFMA burst. Rounds 1/3 drained
// same-phase reads before every MFMA cluster -> reads serialized with MFMA
// chip-wide (the 39% MfmaUtil wall).
//   P1(s): read A-rows-64..127(s) [4 ds]; issue STAGE(s+2) [4 vm];
//          16 MFMA rows 0-63 (frags from P2(s-1)); vmcnt(4); barrier.
//   P2(s): read A-rows-0..63(s+1) + B(s+1) [8 ds] (slot s+1 landed: aged
//          vmcnt(4)+barrier precede); 16 MFMA rows 64-127; barrier.
// Hazards: WAR stage(s+2)->slot(s-1): its reads lgkm-drained before P2(s-1)'s
// MFMAs, chip-wide at end-of-(s-1) barrier, stage issues after. RAW: P2(s)
// reads slot(s+1): vmcnt(4) at P1(s) leaves only stage(s+2) in flight.
// B-frags ping-pong (Bp/Bq) via 2-step unroll (static indexing, rule 20).
// K-accumulation order unchanged -> bit-identical output to rounds 0-3.
__global__ __launch_bounds__(512, 2) void gemm_kernel(
    const ushort* __restrict__ A, const ushort* __restrict__ B,
    const float* __restrict__ bias, float* __restrict__ C) {
  __shared__ __attribute__((aligned(16))) ushort sA[3 * 8192];  // 48 KB
  __shared__ __attribute__((aligned(16))) ushort sB[3 * 8192];  // 48 KB
  const int tid  = threadIdx.x;
  const int lane = tid & 63;
  const int wave = tid >> 6;
  const int wm = wave >> 2;            // 0..1: which 128-row half
  const int wn = wave & 3;             // 0..3: which 64-col quarter
  const int fr  = lane & 15;
  const int fkq = lane >> 4;           // 0..3: 16B chunk of the 32-k row
  const int fchunk = (fkq ^ ((fr >> 1) & 3)) * 8;   // un-swizzled read chunk

  // XCD-chunked block swizzle (bijective: 256 blocks, nwg % 8 == 0)
  const int bid  = blockIdx.x;
  const int xcd  = bid & 7;
  const int i0   = bid >> 3;           // 0..31 within XCD
  const int brow = (xcd >> 1) * 4 + (i0 >> 3);
  const int bcol = (xcd & 1) * 8 + (i0 & 7);
  const size_t arow0 = (size_t)brow * 256;
  const size_t brow0 = (size_t)bcol * 256;

  // staging: thread fills LDS rows tid>>2 and tid>>2+128, chunk tid&3;
  // source column chunk pre-swizzled (rule 21) so LDS dest stays linear.
  const int srow = tid >> 2;                            // 0..127
  const int swz  = ((tid & 3) ^ ((srow >> 1) & 3)) * 8; // source chunk
  const ushort* gA = A + (arow0 + srow) * K2 + swz;
  const ushort* gB = B + (brow0 + srow) * K2 + swz;

  const int rbase = wm * 128;    // wave's row base within the 256-row tile
  const int cbase = wn * 64;     // wave's col base within the 256-col tile

  f32x4 acc[8][4] = {};
  bf16x8 A03[4], A47[4], Bp[4], Bq[4];

#define STAGE(S) do {                                                        \
    const int so_ = ((S) % 3) * 8192;                                        \
    const size_t gk_ = (size_t)(S) * 32;                                     \
    async16(gA + gk_,                     &sA[so_ + tid * 8]);               \
    async16(gA + gk_ + (size_t)128 * K2,  &sA[so_ + (tid + 512) * 8]);       \
    async16(gB + gk_,                     &sB[so_ + tid * 8]);               \
    async16(gB + gk_ + (size_t)128 * K2,  &sB[so_ + (tid + 512) * 8]);       \
  } while (0)
#define FENCE() asm volatile("" ::: "memory")
#define BARRIER() { FENCE(); __builtin_amdgcn_s_barrier(); FENCE(); }

// P1: reads A47(s) for P2, stages s+2, MFMAs rows 0-63 with A03 x BC
// (frags read in P2(s-1) -> compiler emits counted lgkmcnt(4), no drain).
#define PH1(S, BC, DOSTAGE, VMN) do {                                        \
    const int sl_ = ((S) % 3) * 8192;                                        \
    _Pragma("unroll") for (int ii = 0; ii < 4; ++ii)                         \
      A47[ii] = *(const bf16x8*)&sA[sl_ + (rbase + 64 + ii * 16 + fr) * 32 + fchunk]; \
    if (DOSTAGE) STAGE((S) + 2);                                             \
    __builtin_amdgcn_sched_barrier(0);                                       \
    __builtin_amdgcn_s_setprio(1);                                           \
    _Pragma("unroll") for (int jj = 0; jj < 4; ++jj)                         \
      _Pragma("unroll") for (int ii = 0; ii < 4; ++ii)                       \
        acc[ii][jj] = __builtin_amdgcn_mfma_f32_16x16x32_bf16(               \
            A03[ii], BC[jj], acc[ii][jj], 0, 0, 0);                          \
    __builtin_amdgcn_s_setprio(0);                                           \
    __builtin_amdgcn_sched_barrier(0);                                       \
    asm volatile("s_waitcnt vmcnt(" #VMN ")" ::: "memory");                  \
    BARRIER();                                                               \
  } while (0)

// P2: reads A03/B(s+1) for next step's P1, MFMAs rows 64-127 with A47 x BC
// (A47 read in P1(s) -> counted lgkmcnt(8), its wait hidden by P1's MFMAs).
#define PH2(S, BC, BN, DOREAD) do {                                          \
    if (DOREAD) {                                                            \
      const int sl_ = (((S) + 1) % 3) * 8192;                                \
      _Pragma("unroll") for (int ii = 0; ii < 4; ++ii)                       \
        A03[ii] = *(const bf16x8*)&sA[sl_ + (rbase + ii * 16 + fr) * 32 + fchunk]; \
      _Pragma("unroll") for (int jj = 0; jj < 4; ++jj)                       \
        BN[jj] = *(const bf16x8*)&sB[sl_ + (cbase + jj * 16 + fr) * 32 + fchunk];  \
    }                                                                        \
    __builtin_amdgcn_sched_barrier(0);                                       \
    __builtin_amdgcn_s_setprio(1);                                           \
    _Pragma("unroll") for (int jj = 0; jj < 4; ++jj)                         \
      _Pragma("unroll") for (int ii = 0; ii < 4; ++ii)                       \
        acc[4 + ii][jj] = __builtin_amdgcn_mfma_f32_16x16x32_bf16(           \
            A47[ii], BC[jj], acc[4 + ii][jj], 0, 0, 0);                      \
    __builtin_amdgcn_s_setprio(0);                                           \
    __builtin_amdgcn_sched_barrier(0);                                       \
    BARRIER();                                                               \
  } while (0)

  // ---- prologue: stage steps 0,1; wait step 0; pre-read step-0 P1 frags ----
  STAGE(0);
  STAGE(1);
  asm volatile("s_waitcnt vmcnt(4)" ::: "memory");   // step 0 landed
  BARRIER();
#pragma unroll
  for (int ii = 0; ii < 4; ++ii)
    A03[ii] = *(const bf16x8*)&sA[(rbase + ii * 16 + fr) * 32 + fchunk];
#pragma unroll
  for (int jj = 0; jj < 4; ++jj)
    Bp[jj] = *(const bf16x8*)&sB[(cbase + jj * 16 + fr) * 32 + fchunk];

  // ---- main loop: steps 0..127 (all guards static-true) ----
  for (int su = 0; su < 128; su += 2) {
    PH1(su,     Bp, 1, 4);
    PH2(su,     Bp, Bq, 1);
    PH1(su + 1, Bq, 1, 4);
    PH2(su + 1, Bq, Bp, 1);
  }
  // ---- tail: steps 128, 129 (no staging; final drains aged >=2 phases) ----
  PH1(128, Bp, 0, 0);
  PH2(128, Bp, Bq, 1);
  PH1(129, Bq, 0, 0);
  PH2(129, Bq, Bp, 0);

#undef STAGE
#undef FENCE
#undef BARRIER
#undef PH1
#undef PH2

  // ---- epilogue: C = acc + bias (same C/D layout as before) ----
#pragma unroll
  for (int j = 0; j < 4; ++j) {
    const size_t col = brow0 + cbase + j * 16 + fr;
    const float bv = bias[col];
#pragma unroll
    for (int i = 0; i < 8; ++i) {
      const size_t row = arow0 + rbase + i * 16 + fkq * 4;
#pragma unroll
      for (int r = 0; r < 4; ++r)
        C[(row + r) * Ndim + col] = acc[i][j][r] + bv;
    }
  }
}

extern "C" void kernel_launch(void* const* d_in, const int* in_sizes, int n_in,
                              void* d_out, int out_size, void* d_ws, size_t ws_size,
                              hipStream_t stream) {
  const float* x      = (const float*)d_in[0];
  const int*   qw     = (const int*)d_in[1];
  const float* wsc    = (const float*)d_in[2];
  const float* pd     = (const float*)d_in[3];
  const float* pu     = (const float*)d_in[4];
  const float* smooth = (const float*)d_in[5];
  const float* bias   = (const float*)d_in[6];
  float* out = (float*)d_out;

  const size_t abytes = (size_t)Tdim * K2 * 2;          // 34,078,720
  ushort* A    = (ushort*)d_ws;
  ushort* B    = (ushort*)((char*)d_ws + abytes);
  ushort* pdT  = (ushort*)((char*)d_ws + 2 * abytes);   // 32*4096*2 = 256 KB
  float*  part = (float*)((char*)d_ws + 2 * abytes + 262144);  // 16*T*32*4 = 8 MB

  hipLaunchKernelGGL(prep_pdT_kernel, dim3(512),    dim3(256), 0, stream, pd, pdT);
  hipLaunchKernelGGL(prep_a_kernel,   dim3(32, NSPLIT), dim3(256), 0, stream, x, smooth, pdT, A, part);
  hipLaunchKernelGGL(wprep_kernel,    dim3(10240),  dim3(256), 0, stream, qw, wsc, part, pu, A, B);
  hipLaunchKernelGGL(gemm_kernel,     dim3(256),    dim3(512), 0, stream, A, B, bias, out);
}

// Round 6
// 333.817 us; speedup vs baseline: 1.0573x; 1.0068x over previous
//
#include <hip/hip_runtime.h>
#include <hip/hip_bf16.h>
#include <stdint.h>

#define Tdim 4096
#define Ndim 4096
#define Kdim 4096
#define K2   4160   // 4096 + 32 (low-rank concat) + 32 (zero pad to multiple of 64)
#define NSPLIT 16   // K-splits for the low-rank partial GEMM
#define NT   130    // K2 / 32 K-steps for the main GEMM

using f32x4  = __attribute__((ext_vector_type(4))) float;
using bf16x8 = __attribute__((ext_vector_type(8))) short;

// round-to-nearest-even f32 -> bf16 bits
__device__ inline ushort f2bf(float f) {
  union { float f; unsigned u; } v; v.f = f;
  unsigned lsb = (v.u >> 16) & 1u;
  v.u += 0x7fffu + lsb;
  return (ushort)(v.u >> 16);
}

__device__ inline unsigned pack2(float a, float b) {
  return (unsigned)f2bf(a) | ((unsigned)f2bf(b) << 16);
}

__device__ inline float qd(float v, float s) {   // quantize-dequantize
  return fminf(fmaxf(rintf(v / s), -8.f), 7.f) * s;
}

__device__ inline void async16(const void* g, void* l) {
  __builtin_amdgcn_global_load_lds(
      (const __attribute__((address_space(1))) unsigned int*)g,
      (__attribute__((address_space(3))) unsigned int*)l, 16, 0, 0);
}

// ---------------- K0: pdT[n][k] = bf16(pd[k][n])  (32 x 4096) ---------------
__global__ __launch_bounds__(256) void prep_pdT_kernel(
    const float* __restrict__ pd, ushort* __restrict__ pdT) {
  const int idx = blockIdx.x * 256 + threadIdx.x;   // 32*4096 threads
  const int n = idx >> 12;
  const int k = idx & 4095;
  pdT[(size_t)n * Kdim + k] = f2bf(pd[(size_t)k * 32 + n]);
}

// ========== K1: fused activation quant-dequant + low-rank partial GEMM ======
// grid (32 token-tiles, 16 k-splits); block covers 128 tokens x 256 k.
// Writes A[token][0..4095] (bf16 qdq values) and partials[split][T][32].
__global__ __launch_bounds__(256) void prep_a_kernel(
    const float* __restrict__ x, const float* __restrict__ smooth,
    const ushort* __restrict__ pdT, ushort* __restrict__ A,
    float* __restrict__ partials) {
  __shared__ __attribute__((aligned(16))) ushort sXS[128 * 136];  // xs (bf16) for MFMA
  __shared__ __attribute__((aligned(16))) ushort sQ[128 * 136];   // qdq(xs) for A
  const int tid  = threadIdx.x;
  const int lane = tid & 63;
  const int wave = tid >> 6;
  const int fr  = lane & 15;
  const int fkq = lane >> 4;
  const int fk  = fkq * 8;
  const int tok0 = blockIdx.x * 128;
  const int kc0  = blockIdx.y * 256;
  const int r = tid >> 1;          // token row 0..127
  const int g = tid & 1;           // which 64-group of the 128-k chunk
  const int srow2 = tid >> 2;      // A-store: row 0..63 (+64)
  const int scol2 = (tid & 3) * 8; // A-store: col

  f32x4 acc[2][2] = {};

  for (int c = 0; c < 2; ++c) {
    const int kbase = kc0 + c * 128;
    const int kcol  = g * 64;
    const float4* xp = (const float4*)&x[(size_t)(tok0 + r) * Kdim + kbase + kcol];
    const float4* sp = (const float4*)&smooth[kbase + kcol];
    float4 v[16];
#pragma unroll
    for (int q = 0; q < 16; ++q) {
      float4 xv = xp[q], sm = sp[q];
      v[q].x = xv.x * sm.x; v[q].y = xv.y * sm.y;
      v[q].z = xv.z * sm.z; v[q].w = xv.w * sm.w;
    }
    float a = 0.f;
#pragma unroll
    for (int q = 0; q < 16; ++q)
      a = fmaxf(a, fmaxf(fmaxf(fabsf(v[q].x), fabsf(v[q].y)),
                         fmaxf(fabsf(v[q].z), fabsf(v[q].w))));
    const float s = fmaxf(a / 7.0f, 1e-8f);   // exact div: must match np
#pragma unroll
    for (int q2 = 0; q2 < 8; ++q2) {
      const float4 v0 = v[2 * q2], v1 = v[2 * q2 + 1];
      uint4 wx, wq;
      wx.x = pack2(v0.x, v0.y);           wx.y = pack2(v0.z, v0.w);
      wx.z = pack2(v1.x, v1.y);           wx.w = pack2(v1.z, v1.w);
      wq.x = pack2(qd(v0.x, s), qd(v0.y, s)); wq.y = pack2(qd(v0.z, s), qd(v0.w, s));
      wq.z = pack2(qd(v1.x, s), qd(v1.y, s)); wq.w = pack2(qd(v1.z, s), qd(v1.w, s));
      *(uint4*)&sXS[r * 136 + kcol + q2 * 8] = wx;
      *(uint4*)&sQ [r * 136 + kcol + q2 * 8] = wq;
    }
    __syncthreads();

    // low-rank MFMA: t_partial += xs_tile @ pdT_tile (B fragments via vec loads)
#pragma unroll
    for (int kk = 0; kk < 4; ++kk) {
      const int kglob = kbase + kk * 32 + fk;
      bf16x8 af0 = *(const bf16x8*)&sXS[(wave * 32 + fr) * 136 + kk * 32 + fk];
      bf16x8 af1 = *(const bf16x8*)&sXS[(wave * 32 + 16 + fr) * 136 + kk * 32 + fk];
      bf16x8 b0 = *(const bf16x8*)&pdT[(size_t)fr * Kdim + kglob];
      bf16x8 b1 = *(const bf16x8*)&pdT[(size_t)(16 + fr) * Kdim + kglob];
      acc[0][0] = __builtin_amdgcn_mfma_f32_16x16x32_bf16(af0, b0, acc[0][0], 0, 0, 0);
      acc[0][1] = __builtin_amdgcn_mfma_f32_16x16x32_bf16(af0, b1, acc[0][1], 0, 0, 0);
      acc[1][0] = __builtin_amdgcn_mfma_f32_16x16x32_bf16(af1, b0, acc[1][0], 0, 0, 0);
      acc[1][1] = __builtin_amdgcn_mfma_f32_16x16x32_bf16(af1, b1, acc[1][1], 0, 0, 0);
    }

    // coalesced A store from sQ
#pragma unroll
    for (int h = 0; h < 2; ++h) {
      const int rr = srow2 + h * 64;
#pragma unroll
      for (int u = 0; u < 4; ++u)
        *(uint4*)&A[(size_t)(tok0 + rr) * K2 + kbase + scol2 + u * 32] =
            *(const uint4*)&sQ[rr * 136 + scol2 + u * 32];
    }
    __syncthreads();
  }

  float* P = partials + (size_t)blockIdx.y * Tdim * 32;
#pragma unroll
  for (int i = 0; i < 2; ++i) {
    const int row0 = tok0 + wave * 32 + i * 16 + fkq * 4;
#pragma unroll
    for (int j = 0; j < 2; ++j) {
      const int col = j * 16 + fr;
#pragma unroll
      for (int rr = 0; rr < 4; ++rr)
        P[(size_t)(row0 + rr) * 32 + col] = acc[i][j][rr];
    }
  }
}

// ====== K2: weight dequant (bid<8192) | A-tail reduce (8192..9215) | B-tail ==
__global__ __launch_bounds__(256) void wprep_kernel(
    const int* __restrict__ qw, const float* __restrict__ wsc,
    const float* __restrict__ partials, const float* __restrict__ pu,
    ushort* __restrict__ A, ushort* __restrict__ B) {
  const int bid = blockIdx.x;
  if (bid < 8192) {
    // dequantize int4 weights -> B' bf16, 8 elems/thread
    const size_t idx = ((size_t)bid * 256 + threadIdx.x) * 8;
    const int n = (int)(idx >> 12);
    const int k = (int)(idx & 4095);
    const float s = wsc[n * 64 + (k >> 6)];
    const int4 q0 = *(const int4*)(qw + idx);
    const int4 q1 = *(const int4*)(qw + idx + 4);
    uint4 o;
    o.x = pack2((float)q0.x * s, (float)q0.y * s);
    o.y = pack2((float)q0.z * s, (float)q0.w * s);
    o.z = pack2((float)q1.x * s, (float)q1.y * s);
    o.w = pack2((float)q1.z * s, (float)q1.w * s);
    *(uint4*)(B + (size_t)n * K2 + k) = o;
  } else if (bid < 8192 + 1024) {
    // reduce K-split partials -> bf16 into A tail cols [4096..4160)
    const int idx = (bid - 8192) * 256 + threadIdx.x;   // T*64 threads
    const int token = idx >> 6, c = idx & 63;
    ushort v = 0;
    if (c < 32) {
      float s = 0.f;
#pragma unroll
      for (int p = 0; p < NSPLIT; ++p)
        s += partials[(size_t)p * Tdim * 32 + (size_t)token * 32 + c];
      v = f2bf(s);
    }
    A[(size_t)token * K2 + Kdim + c] = v;
  } else {
    // B tail cols = [bf16(pu^T) | zeros]
    const int idx = (bid - 9216) * 256 + threadIdx.x;   // N*64 threads
    const int n = idx >> 6, c = idx & 63;
    ushort v = 0;
    if (c < 32) v = f2bf(pu[(size_t)c * Ndim + n]);     // proj_up is [32, N]
    B[(size_t)n * K2 + Kdim + c] = v;
  }
}

// ========== K3: C = A' @ B'^T + bias  (read-ahead 2-phase, CLOBBER-FREE) ====
// IDENTICAL kernel body to round 5; the round-5 crash was the LAUNCH GRID
// typo (dim3(32*32)=1024 blocks vs the 256-block bijective swizzle -> OOB
// reads/writes -> fault). Grid restored to dim3(256); the clobber-free
// experiment runs for real this time.
//
// Schedule (as round 4): 256x256 tile, 8 waves, BK=32, ring-3 slots,
// stage-2-ahead, read-ahead fragments. The ONE variable vs round 4: no
// "memory" clobbers / no FENCE() pairs. A "memory"-clobbered asm is
// mayLoad|mayStore to the waitcnt pass, which inserts a hidden
// s_waitcnt vmcnt(0) lgkmcnt(0) before it -- that drained every in-flight
// staging load and ds_read at every phase boundary in rounds 0-4,
// serializing the LDS pipe (~1530 cyc/step) with the MFMA pipe (~1242
// cyc/step) = the invariant 2769 cyc/step @ 39% MfmaUtil. Ordering is now
// enforced by sched_barrier(0) only (rule #18; the m201 template's
// clobber-free pattern). Hazard ledger unchanged:
//   WAR stage(s+2)->slot(s-1): those reads were consumed by MFMAs before
//     the end-of-(s-1) barrier, chip-wide.
//   RAW reads(slot s+1): counted vmcnt(4) at end of PH1(s) + barrier.
// ds_read->MFMA deps: compiler-inserted COUNTED lgkmcnt; fresh reads stay
// outstanding under the MFMA bursts (the m218 mechanism).
// K-accumulation order unchanged -> bit-identical output.
__global__ __launch_bounds__(512, 2) void gemm_kernel(
    const ushort* __restrict__ A, const ushort* __restrict__ B,
    const float* __restrict__ bias, float* __restrict__ C) {
  __shared__ __attribute__((aligned(16))) ushort sA[3 * 8192];  // 48 KB
  __shared__ __attribute__((aligned(16))) ushort sB[3 * 8192];  // 48 KB
  const int tid  = threadIdx.x;
  const int lane = tid & 63;
  const int wave = tid >> 6;
  const int wm = wave >> 2;            // 0..1: which 128-row half
  const int wn = wave & 3;             // 0..3: which 64-col quarter
  const int fr  = lane & 15;
  const int fkq = lane >> 4;           // 0..3: 16B chunk of the 32-k row
  const int fchunk = (fkq ^ ((fr >> 1) & 3)) * 8;   // un-swizzled read chunk

  // XCD-chunked block swizzle (bijective: 256 blocks, nwg % 8 == 0)
  const int bid  = blockIdx.x;
  const int xcd  = bid & 7;
  const int i0   = bid >> 3;           // 0..31 within XCD
  const int brow = (xcd >> 1) * 4 + (i0 >> 3);
  const int bcol = (xcd & 1) * 8 + (i0 & 7);
  const size_t arow0 = (size_t)brow * 256;
  const size_t brow0 = (size_t)bcol * 256;

  // staging: thread fills LDS rows tid>>2 and tid>>2+128, chunk tid&3;
  // source column chunk pre-swizzled (rule 21) so LDS dest stays linear.
  const int srow = tid >> 2;                            // 0..127
  const int swz  = ((tid & 3) ^ ((srow >> 1) & 3)) * 8; // source chunk
  const ushort* gA = A + (arow0 + srow) * K2 + swz;
  const ushort* gB = B + (brow0 + srow) * K2 + swz;

  const int rbase = wm * 128;    // wave's row base within the 256-row tile
  const int cbase = wn * 64;     // wave's col base within the 256-col tile

  f32x4 acc[8][4] = {};
  bf16x8 A03[4], A47[4], Bp[4], Bq[4];

#define SB() __builtin_amdgcn_sched_barrier(0)
#define STAGE(S) do {                                                        \
    const int so_ = ((S) % 3) * 8192;                                        \
    const size_t gk_ = (size_t)(S) * 32;                                     \
    async16(gA + gk_,                     &sA[so_ + tid * 8]);               \
    async16(gA + gk_ + (size_t)128 * K2,  &sA[so_ + (tid + 512) * 8]);       \
    async16(gB + gk_,                     &sB[so_ + tid * 8]);               \
    async16(gB + gk_ + (size_t)128 * K2,  &sB[so_ + (tid + 512) * 8]);       \
  } while (0)

// P1: reads A47(s) for P2, stages s+2, MFMAs rows 0-63 with A03 x BC
// (frags read in P2(s-1); compiler emits counted lgkmcnt, no drain).
#define PH1(S, BC, DOSTAGE, VMN) do {                                        \
    const int sl_ = ((S) % 3) * 8192;                                        \
    _Pragma("unroll") for (int ii = 0; ii < 4; ++ii)                         \
      A47[ii] = *(const bf16x8*)&sA[sl_ + (rbase + 64 + ii * 16 + fr) * 32 + fchunk]; \
    if (DOSTAGE) STAGE((S) + 2);                                             \
    SB();                                                                    \
    __builtin_amdgcn_s_setprio(1);                                           \
    _Pragma("unroll") for (int jj = 0; jj < 4; ++jj)                         \
      _Pragma("unroll") for (int ii = 0; ii < 4; ++ii)                       \
        acc[ii][jj] = __builtin_amdgcn_mfma_f32_16x16x32_bf16(               \
            A03[ii], BC[jj], acc[ii][jj], 0, 0, 0);                          \
    __builtin_amdgcn_s_setprio(0);                                           \
    SB();                                                                    \
    asm volatile("s_waitcnt vmcnt(" #VMN ")");                               \
    SB();                                                                    \
    __builtin_amdgcn_s_barrier();                                            \
    SB();                                                                    \
  } while (0)

// P2: reads A03/B(s+1) for next step's P1, MFMAs rows 64-127 with A47 x BC
// (A47 read in P1(s); counted lgkmcnt leaves the 8 fresh reads in flight).
#define PH2(S, BC, BN, DOREAD) do {                                          \
    if (DOREAD) {                                                            \
      const int sl_ = (((S) + 1) % 3) * 8192;                                \
      _Pragma("unroll") for (int ii = 0; ii < 4; ++ii)                       \
        A03[ii] = *(const bf16x8*)&sA[sl_ + (rbase + ii * 16 + fr) * 32 + fchunk]; \
      _Pragma("unroll") for (int jj = 0; jj < 4; ++jj)                       \
        BN[jj] = *(const bf16x8*)&sB[sl_ + (cbase + jj * 16 + fr) * 32 + fchunk];  \
    }                                                                        \
    SB();                                                                    \
    __builtin_amdgcn_s_setprio(1);                                           \
    _Pragma("unroll") for (int jj = 0; jj < 4; ++jj)                         \
      _Pragma("unroll") for (int ii = 0; ii < 4; ++ii)                       \
        acc[4 + ii][jj] = __builtin_amdgcn_mfma_f32_16x16x32_bf16(           \
            A47[ii], BC[jj], acc[4 + ii][jj], 0, 0, 0);                      \
    __builtin_amdgcn_s_setprio(0);                                           \
    SB();                                                                    \
    __builtin_amdgcn_s_barrier();                                            \
    SB();                                                                    \
  } while (0)

  // ---- prologue: stage steps 0,1; wait step 0; pre-read step-0 P1 frags ----
  STAGE(0);
  STAGE(1);
  SB();
  asm volatile("s_waitcnt vmcnt(4)");   // step 0 landed
  SB();
  __builtin_amdgcn_s_barrier();
  SB();
#pragma unroll
  for (int ii = 0; ii < 4; ++ii)
    A03[ii] = *(const bf16x8*)&sA[(rbase + ii * 16 + fr) * 32 + fchunk];
#pragma unroll
  for (int jj = 0; jj < 4; ++jj)
    Bp[jj] = *(const bf16x8*)&sB[(cbase + jj * 16 + fr) * 32 + fchunk];

  // ---- main loop: steps 0..127 (all guards static-true) ----
  for (int su = 0; su < 128; su += 2) {
    PH1(su,     Bp, 1, 4);
    PH2(su,     Bp, Bq, 1);
    PH1(su + 1, Bq, 1, 4);
    PH2(su + 1, Bq, Bp, 1);
  }
  // ---- tail: steps 128, 129 (no staging; final drains aged >=2 phases) ----
  PH1(128, Bp, 0, 0);
  PH2(128, Bp, Bq, 1);
  PH1(129, Bq, 0, 0);
  PH2(129, Bq, Bp, 0);

#undef SB
#undef STAGE
#undef PH1
#undef PH2

  // ---- epilogue: C = acc + bias (same C/D layout as before) ----
#pragma unroll
  for (int j = 0; j < 4; ++j) {
    const size_t col = brow0 + cbase + j * 16 + fr;
    const float bv = bias[col];
#pragma unroll
    for (int i = 0; i < 8; ++i) {
      const size_t row = arow0 + rbase + i * 16 + fkq * 4;
#pragma unroll
      for (int r = 0; r < 4; ++r)
        C[(row + r) * Ndim + col] = acc[i][j][r] + bv;
    }
  }
}

extern "C" void kernel_launch(void* const* d_in, const int* in_sizes, int n_in,
                              void* d_out, int out_size, void* d_ws, size_t ws_size,
                              hipStream_t stream) {
  const float* x      = (const float*)d_in[0];
  const int*   qw     = (const int*)d_in[1];
  const float* wsc    = (const float*)d_in[2];
  const float* pd     = (const float*)d_in[3];
  const float* pu     = (const float*)d_in[4];
  const float* smooth = (const float*)d_in[5];
  const float* bias   = (const float*)d_in[6];
  float* out = (float*)d_out;

  const size_t abytes = (size_t)Tdim * K2 * 2;          // 34,078,720
  ushort* A    = (ushort*)d_ws;
  ushort* B    = (ushort*)((char*)d_ws + abytes);
  ushort* pdT  = (ushort*)((char*)d_ws + 2 * abytes);   // 32*4096*2 = 256 KB
  float*  part = (float*)((char*)d_ws + 2 * abytes + 262144);  // 16*T*32*4 = 8 MB

  hipLaunchKernelGGL(prep_pdT_kernel, dim3(512),    dim3(256), 0, stream, pd, pdT);
  hipLaunchKernelGGL(prep_a_kernel,   dim3(32, NSPLIT), dim3(256), 0, stream, x, smooth, pdT, A, part);
  hipLaunchKernelGGL(wprep_kernel,    dim3(10240),  dim3(256), 0, stream, qw, wsc, part, pu, A, B);
  hipLaunchKernelGGL(gemm_kernel,     dim3(256),    dim3(512), 0, stream, A, B, bias, out);
}

// Round 7
// 326.324 us; speedup vs baseline: 1.0816x; 1.0230x over previous
//
#include <hip/hip_runtime.h>
#include <hip/hip_bf16.h>
#include <stdint.h>

#define Tdim 4096
#define Ndim 4096
#define Kdim 4096
#define K2   4160   // 4096 + 32 (low-rank concat) + 32 (zero pad to multiple of 64)
#define NSPLIT 16   // K-splits for the low-rank partial GEMM
#define NT   130    // K2 / 32 K-steps for the main GEMM

using f32x4  = __attribute__((ext_vector_type(4))) float;
using bf16x8 = __attribute__((ext_vector_type(8))) short;

// round-to-nearest-even f32 -> bf16 bits
__device__ inline ushort f2bf(float f) {
  union { float f; unsigned u; } v; v.f = f;
  unsigned lsb = (v.u >> 16) & 1u;
  v.u += 0x7fffu + lsb;
  return (ushort)(v.u >> 16);
}

__device__ inline unsigned pack2(float a, float b) {
  return (unsigned)f2bf(a) | ((unsigned)f2bf(b) << 16);
}

__device__ inline float qd(float v, float s) {   // quantize-dequantize
  return fminf(fmaxf(rintf(v / s), -8.f), 7.f) * s;
}

__device__ inline void async16(const void* g, void* l) {
  __builtin_amdgcn_global_load_lds(
      (const __attribute__((address_space(1))) unsigned int*)g,
      (__attribute__((address_space(3))) unsigned int*)l, 16, 0, 0);
}

// ---------------- K0: pdT[n][k] = bf16(pd[k][n])  (32 x 4096) ---------------
__global__ __launch_bounds__(256) void prep_pdT_kernel(
    const float* __restrict__ pd, ushort* __restrict__ pdT) {
  const int idx = blockIdx.x * 256 + threadIdx.x;   // 32*4096 threads
  const int n = idx >> 12;
  const int k = idx & 4095;
  pdT[(size_t)n * Kdim + k] = f2bf(pd[(size_t)k * 32 + n]);
}

// ========== K1: fused activation quant-dequant + low-rank partial GEMM ======
// grid (32 token-tiles, 16 k-splits); block covers 128 tokens x 256 k.
// Writes A[token][0..4095] (bf16 qdq values) and partials[split][T][32].
__global__ __launch_bounds__(256) void prep_a_kernel(
    const float* __restrict__ x, const float* __restrict__ smooth,
    const ushort* __restrict__ pdT, ushort* __restrict__ A,
    float* __restrict__ partials) {
  __shared__ __attribute__((aligned(16))) ushort sXS[128 * 136];  // xs (bf16) for MFMA
  __shared__ __attribute__((aligned(16))) ushort sQ[128 * 136];   // qdq(xs) for A
  const int tid  = threadIdx.x;
  const int lane = tid & 63;
  const int wave = tid >> 6;
  const int fr  = lane & 15;
  const int fkq = lane >> 4;
  const int fk  = fkq * 8;
  const int tok0 = blockIdx.x * 128;
  const int kc0  = blockIdx.y * 256;
  const int r = tid >> 1;          // token row 0..127
  const int g = tid & 1;           // which 64-group of the 128-k chunk
  const int srow2 = tid >> 2;      // A-store: row 0..63 (+64)
  const int scol2 = (tid & 3) * 8; // A-store: col

  f32x4 acc[2][2] = {};

  for (int c = 0; c < 2; ++c) {
    const int kbase = kc0 + c * 128;
    const int kcol  = g * 64;
    const float4* xp = (const float4*)&x[(size_t)(tok0 + r) * Kdim + kbase + kcol];
    const float4* sp = (const float4*)&smooth[kbase + kcol];
    float4 v[16];
#pragma unroll
    for (int q = 0; q < 16; ++q) {
      float4 xv = xp[q], sm = sp[q];
      v[q].x = xv.x * sm.x; v[q].y = xv.y * sm.y;
      v[q].z = xv.z * sm.z; v[q].w = xv.w * sm.w;
    }
    float a = 0.f;
#pragma unroll
    for (int q = 0; q < 16; ++q)
      a = fmaxf(a, fmaxf(fmaxf(fabsf(v[q].x), fabsf(v[q].y)),
                         fmaxf(fabsf(v[q].z), fabsf(v[q].w))));
    const float s = fmaxf(a / 7.0f, 1e-8f);   // exact div: must match np
#pragma unroll
    for (int q2 = 0; q2 < 8; ++q2) {
      const float4 v0 = v[2 * q2], v1 = v[2 * q2 + 1];
      uint4 wx, wq;
      wx.x = pack2(v0.x, v0.y);           wx.y = pack2(v0.z, v0.w);
      wx.z = pack2(v1.x, v1.y);           wx.w = pack2(v1.z, v1.w);
      wq.x = pack2(qd(v0.x, s), qd(v0.y, s)); wq.y = pack2(qd(v0.z, s), qd(v0.w, s));
      wq.z = pack2(qd(v1.x, s), qd(v1.y, s)); wq.w = pack2(qd(v1.z, s), qd(v1.w, s));
      *(uint4*)&sXS[r * 136 + kcol + q2 * 8] = wx;
      *(uint4*)&sQ [r * 136 + kcol + q2 * 8] = wq;
    }
    __syncthreads();

    // low-rank MFMA: t_partial += xs_tile @ pdT_tile (B fragments via vec loads)
#pragma unroll
    for (int kk = 0; kk < 4; ++kk) {
      const int kglob = kbase + kk * 32 + fk;
      bf16x8 af0 = *(const bf16x8*)&sXS[(wave * 32 + fr) * 136 + kk * 32 + fk];
      bf16x8 af1 = *(const bf16x8*)&sXS[(wave * 32 + 16 + fr) * 136 + kk * 32 + fk];
      bf16x8 b0 = *(const bf16x8*)&pdT[(size_t)fr * Kdim + kglob];
      bf16x8 b1 = *(const bf16x8*)&pdT[(size_t)(16 + fr) * Kdim + kglob];
      acc[0][0] = __builtin_amdgcn_mfma_f32_16x16x32_bf16(af0, b0, acc[0][0], 0, 0, 0);
      acc[0][1] = __builtin_amdgcn_mfma_f32_16x16x32_bf16(af0, b1, acc[0][1], 0, 0, 0);
      acc[1][0] = __builtin_amdgcn_mfma_f32_16x16x32_bf16(af1, b0, acc[1][0], 0, 0, 0);
      acc[1][1] = __builtin_amdgcn_mfma_f32_16x16x32_bf16(af1, b1, acc[1][1], 0, 0, 0);
    }

    // coalesced A store from sQ
#pragma unroll
    for (int h = 0; h < 2; ++h) {
      const int rr = srow2 + h * 64;
#pragma unroll
      for (int u = 0; u < 4; ++u)
        *(uint4*)&A[(size_t)(tok0 + rr) * K2 + kbase + scol2 + u * 32] =
            *(const uint4*)&sQ[rr * 136 + scol2 + u * 32];
    }
    __syncthreads();
  }

  float* P = partials + (size_t)blockIdx.y * Tdim * 32;
#pragma unroll
  for (int i = 0; i < 2; ++i) {
    const int row0 = tok0 + wave * 32 + i * 16 + fkq * 4;
#pragma unroll
    for (int j = 0; j < 2; ++j) {
      const int col = j * 16 + fr;
#pragma unroll
      for (int rr = 0; rr < 4; ++rr)
        P[(size_t)(row0 + rr) * 32 + col] = acc[i][j][rr];
    }
  }
}

// ====== K2: weight dequant (bid<8192) | A-tail reduce (8192..9215) | B-tail ==
__global__ __launch_bounds__(256) void wprep_kernel(
    const int* __restrict__ qw, const float* __restrict__ wsc,
    const float* __restrict__ partials, const float* __restrict__ pu,
    ushort* __restrict__ A, ushort* __restrict__ B) {
  const int bid = blockIdx.x;
  if (bid < 8192) {
    // dequantize int4 weights -> B' bf16, 8 elems/thread
    const size_t idx = ((size_t)bid * 256 + threadIdx.x) * 8;
    const int n = (int)(idx >> 12);
    const int k = (int)(idx & 4095);
    const float s = wsc[n * 64 + (k >> 6)];
    const int4 q0 = *(const int4*)(qw + idx);
    const int4 q1 = *(const int4*)(qw + idx + 4);
    uint4 o;
    o.x = pack2((float)q0.x * s, (float)q0.y * s);
    o.y = pack2((float)q0.z * s, (float)q0.w * s);
    o.z = pack2((float)q1.x * s, (float)q1.y * s);
    o.w = pack2((float)q1.z * s, (float)q1.w * s);
    *(uint4*)(B + (size_t)n * K2 + k) = o;
  } else if (bid < 8192 + 1024) {
    // reduce K-split partials -> bf16 into A tail cols [4096..4160)
    const int idx = (bid - 8192) * 256 + threadIdx.x;   // T*64 threads
    const int token = idx >> 6, c = idx & 63;
    ushort v = 0;
    if (c < 32) {
      float s = 0.f;
#pragma unroll
      for (int p = 0; p < NSPLIT; ++p)
        s += partials[(size_t)p * Tdim * 32 + (size_t)token * 32 + c];
      v = f2bf(s);
    }
    A[(size_t)token * K2 + Kdim + c] = v;
  } else {
    // B tail cols = [bf16(pu^T) | zeros]
    const int idx = (bid - 9216) * 256 + threadIdx.x;   // N*64 threads
    const int n = idx >> 6, c = idx & 63;
    ushort v = 0;
    if (c < 32) v = f2bf(pu[(size_t)c * Ndim + n]);     // proj_up is [32, N]
    B[(size_t)n * K2 + Kdim + c] = v;
  }
}

// ========== K3: C = A' @ B'^T + bias  (128x256 tile, 2 blocks/CU) ===========
// ROUND-7 VARIABLE: cross-block overlap. Rounds 0-6 all used one 512-thread
// block per CU -- every s_barrier resynced all 8 resident waves, so LDS
// service (~1530 cyc/step) and MFMA (~1242 cyc/step) serialized chip-wide in
// five different schedules (invariant 2769 cyc/step @ 39% MfmaUtil). This
// version: 128x256 tile, 4 waves (256 thr), 72 KB LDS -> TWO independent
// blocks per CU. While block A drains its lgkm/barrier, block B's waves feed
// the matrix pipe (the m114/m97 implicit-overlap mechanism, robust to
// codegen). Same LDS-bytes-per-FLOP as the 256sq tile (reuse is symmetric:
// A-frags shared by 2 waves, B-frags by 2). Ring-3 BK=32 slots, stage-2-
// ahead, counted vmcnt(6), ONE barrier per step, proven chunk-XOR swizzle
// via pre-swizzled global source (rule 21). Hazard ledger (as rounds 1-6,
// numerics-verified): RAW slot(s+1): vmcnt(6)+barrier at end of s; WAR
// stage(s+2)->slot(s-1): its reads were lgkm-consumed by s-1's MFMAs before
// the end-of-(s-1) barrier. K-accumulation order unchanged -> same absmax.
__global__ __launch_bounds__(256, 2) void gemm_kernel(
    const ushort* __restrict__ A, const ushort* __restrict__ B,
    const float* __restrict__ bias, float* __restrict__ C) {
  __shared__ __attribute__((aligned(16))) ushort sA[3 * 4096];  // 24 KB
  __shared__ __attribute__((aligned(16))) ushort sB[3 * 8192];  // 48 KB
  const int tid  = threadIdx.x;
  const int lane = tid & 63;
  const int wave = tid >> 6;           // 0..3
  const int wm  = wave >> 1;           // 0..1: which 64-row half
  const int wnn = wave & 1;            // 0..1: which 128-col half
  const int fr  = lane & 15;
  const int fkq = lane >> 4;           // 0..3: 16B chunk of the 32-k row
  const int fchunk = (fkq ^ ((fr >> 1) & 3)) * 8;   // un-swizzled read chunk

  // XCD-chunked block swizzle over the 32x16 (M x N) tile grid.
  // 512 blocks, nwg % 8 == 0 -> bijective. Each XCD owns an 8x8 region.
  const int bid  = blockIdx.x;
  const int xcd  = bid & 7;
  const int i0   = bid >> 3;           // 0..63 within XCD
  const int brow = (xcd >> 1) * 8 + (i0 & 7);    // 0..31
  const int bcol = (xcd & 1) * 8 + (i0 >> 3);    // 0..15
  const size_t arow0 = (size_t)brow * 128;
  const size_t brow0 = (size_t)bcol * 256;

  // staging: 256 threads; thread fills LDS row tid>>2 (+64/+128/+192 for the
  // extra calls), chunk tid&3; source chunk pre-swizzled so dest is linear.
  const int srow = tid >> 2;                            // 0..63
  const int swz  = ((tid & 3) ^ ((srow >> 1) & 3)) * 8; // source chunk
  const ushort* gA = A + (arow0 + srow) * K2 + swz;
  const ushort* gB = B + (brow0 + srow) * K2 + swz;

  const int rbase = wm * 64;     // wave's row base within the 128-row tile
  const int cbase = wnn * 128;   // wave's col base within the 256-col tile

  f32x4 acc[4][8] = {};

#define SB() __builtin_amdgcn_sched_barrier(0)
  // stage K-step S into slots (A: SLA elems, B: SLB elems). 6 loads.
#define STAGE(S, SLA, SLB) do {                                              \
    const size_t gk_ = (size_t)(S) * 32;                                     \
    async16(gA + gk_,                     &sA[(SLA) + tid * 8]);             \
    async16(gA + gk_ + (size_t)64  * K2,  &sA[(SLA) + (tid + 256) * 8]);     \
    async16(gB + gk_,                     &sB[(SLB) + tid * 8]);             \
    async16(gB + gk_ + (size_t)64  * K2,  &sB[(SLB) + (tid + 256) * 8]);     \
    async16(gB + gk_ + (size_t)128 * K2,  &sB[(SLB) + (tid + 512) * 8]);     \
    async16(gB + gk_ + (size_t)192 * K2,  &sB[(SLB) + (tid + 768) * 8]);     \
  } while (0)

  // ---- prologue: stage steps 0,1; wait step 0 (counted: leave step 1) ----
  STAGE(0, 0, 0);
  STAGE(1, 4096, 8192);
  SB();
  asm volatile("s_waitcnt vmcnt(6)");
  SB();
  __builtin_amdgcn_s_barrier();
  SB();

  int ms = 0, mt = 2;   // s % 3 and (s+2) % 3
  for (int s = 0; s < NT; ++s) {
    const int slA = ms << 12;          // ms * 4096
    const int slB = ms << 13;          // ms * 8192

    // fragment reads (4 A + 8 B ds_read_b128); compiler-counted lgkm lets
    // early MFMAs start while later B-reads are still in the LDS pipe.
    bf16x8 af[4], bfr[8];
#pragma unroll
    for (int ii = 0; ii < 4; ++ii)
      af[ii] = *(const bf16x8*)&sA[slA + (rbase + ii * 16 + fr) * 32 + fchunk];
#pragma unroll
    for (int jj = 0; jj < 8; ++jj)
      bfr[jj] = *(const bf16x8*)&sB[slB + (cbase + jj * 16 + fr) * 32 + fchunk];

    if (s < NT - 2) STAGE(s + 2, mt << 12, mt << 13);

    __builtin_amdgcn_s_setprio(1);
#pragma unroll
    for (int jj = 0; jj < 8; ++jj)
#pragma unroll
      for (int ii = 0; ii < 4; ++ii)
        acc[ii][jj] = __builtin_amdgcn_mfma_f32_16x16x32_bf16(
            af[ii], bfr[jj], acc[ii][jj], 0, 0, 0);
    __builtin_amdgcn_s_setprio(0);

    SB();
    if (s < NT - 2)       asm volatile("s_waitcnt vmcnt(6)");  // s+1 landed
    else if (s == NT - 2) asm volatile("s_waitcnt vmcnt(0)");
    SB();
    __builtin_amdgcn_s_barrier();
    SB();

    ms = (ms == 2) ? 0 : ms + 1;
    mt = (mt == 2) ? 0 : mt + 1;
  }
#undef SB
#undef STAGE

  // ---- epilogue: C = acc + bias (same C/D layout as before) ----
#pragma unroll
  for (int j = 0; j < 8; ++j) {
    const size_t col = brow0 + cbase + j * 16 + fr;
    const float bv = bias[col];
#pragma unroll
    for (int i = 0; i < 4; ++i) {
      const size_t row = arow0 + rbase + i * 16 + fkq * 4;
#pragma unroll
      for (int r = 0; r < 4; ++r)
        C[(row + r) * Ndim + col] = acc[i][j][r] + bv;
    }
  }
}

extern "C" void kernel_launch(void* const* d_in, const int* in_sizes, int n_in,
                              void* d_out, int out_size, void* d_ws, size_t ws_size,
                              hipStream_t stream) {
  const float* x      = (const float*)d_in[0];
  const int*   qw     = (const int*)d_in[1];
  const float* wsc    = (const float*)d_in[2];
  const float* pd     = (const float*)d_in[3];
  const float* pu     = (const float*)d_in[4];
  const float* smooth = (const float*)d_in[5];
  const float* bias   = (const float*)d_in[6];
  float* out = (float*)d_out;

  const size_t abytes = (size_t)Tdim * K2 * 2;          // 34,078,720
  ushort* A    = (ushort*)d_ws;
  ushort* B    = (ushort*)((char*)d_ws + abytes);
  ushort* pdT  = (ushort*)((char*)d_ws + 2 * abytes);   // 32*4096*2 = 256 KB
  float*  part = (float*)((char*)d_ws + 2 * abytes + 262144);  // 16*T*32*4 = 8 MB

  hipLaunchKernelGGL(prep_pdT_kernel, dim3(512),    dim3(256), 0, stream, pd, pdT);
  hipLaunchKernelGGL(prep_a_kernel,   dim3(32, NSPLIT), dim3(256), 0, stream, x, smooth, pdT, A, part);
  hipLaunchKernelGGL(wprep_kernel,    dim3(10240),  dim3(256), 0, stream, qw, wsc, part, pu, A, B);
  hipLaunchKernelGGL(gemm_kernel,     dim3(512),    dim3(256), 0, stream, A, B, bias, out);
}